// Round 1
// baseline (19344.066 us; speedup 1.0000x reference)
//
#include <hip/hip_runtime.h>
#include <math.h>

// MobiusGRU (hyperbolic GRU), T=256 B=64 D=H=512, 2 layers, f32.
// Structure:
//   per layer: [transpose W_ih] -> [GEMM X@W_ihT] -> [row nonlin (mobius_matvec tail)]
//              -> [transpose W_hh] -> [sequential scan, 64 WGs = 1 per batch row]
//   Batch rows are independent -> scan needs only __syncthreads().
//   out1 (layer-1 outputs) staged in d_out's out2 region: fully consumed by
//   layer-2 GEMM/nonlin before scan-2 overwrites it with out2.

#define T_  256
#define B_  64
#define H_  512
#define G3_ 1536
#define EPSF 1e-15f
#define CLIPF (1.0f - 1e-5f)

__device__ __forceinline__ float artanh_c(float x){
  x = fminf(fmaxf(x, -CLIPF), CLIPF);
  return 0.5f * logf((1.0f + x) / (1.0f - x));
}
__device__ __forceinline__ float sigmoidf_(float x){
  return 1.0f / (1.0f + expf(-x));
}

// multi-scalar block reduction over 256 threads (4 waves of 64)
template<int NS>
__device__ __forceinline__ void block_reduce(float (&v)[NS], float* red, int tid){
  #pragma unroll
  for (int off = 32; off > 0; off >>= 1){
    #pragma unroll
    for (int s = 0; s < NS; s++) v[s] += __shfl_xor(v[s], off);
  }
  const int wave = tid >> 6;
  if ((tid & 63) == 0){
    #pragma unroll
    for (int s = 0; s < NS; s++) red[s*4 + wave] = v[s];
  }
  __syncthreads();
  #pragma unroll
  for (int s = 0; s < NS; s++) v[s] = red[s*4+0] + red[s*4+1] + red[s*4+2] + red[s*4+3];
  __syncthreads();
}

// ---- prep: transpose weight_ih [1536][512] -> WihT [512][1536]
__global__ void k_prep_ih(const float* __restrict__ Wih, float* __restrict__ WihT){
  int i = blockIdx.x * blockDim.x + threadIdx.x;
  if (i >= H_ * G3_) return;
  int k = i / G3_, n = i % G3_;
  WihT[i] = Wih[n * H_ + k];
}

// ---- prep: weight_hh [1536][512] -> WzrT [512][1024] (cols: z|r), WhhT [512][512] (candidate)
// split order of weight_hh rows: [0:512)=W_hr, [512:1024)=W_hh(candidate), [1024:1536)=W_hz
__global__ void k_prep_hh(const float* __restrict__ Whh, float* __restrict__ WzrT,
                          float* __restrict__ WhhT){
  int i = blockIdx.x * blockDim.x + threadIdx.x;
  if (i < H_ * 1024){
    int k = i / 1024, j2 = i % 1024;
    int row = (j2 < H_) ? (1024 + j2) : (j2 - H_);  // z then r
    WzrT[i] = Whh[row * H_ + k];
  } else {
    int i2 = i - H_ * 1024;
    if (i2 < H_ * H_){
      int k = i2 / H_, j = i2 % H_;
      WhhT[i2] = Whh[(H_ + j) * H_ + k];
    }
  }
}

// ---- tiled f32 GEMM: C[M=16384][N=1536] = A[M][512] * Bt[512][N]
__global__ __launch_bounds__(256) void k_gemm(const float* __restrict__ A,
                                              const float* __restrict__ Bt,
                                              float* __restrict__ C){
  const int M = T_ * B_, N = G3_, K = H_;
  const int mbase = blockIdx.x * 64, nbase = blockIdx.y * 64;
  __shared__ float As[32][65];  // [k][m]
  __shared__ float Bs[32][65];  // [k][n]
  const int tid = threadIdx.x;
  const int tm = tid >> 4, tn = tid & 15;
  float acc[4][4] = {};
  for (int k0 = 0; k0 < K; k0 += 32){
    #pragma unroll
    for (int i = 0; i < 8; i++){
      int e = tid + 256*i;
      int m = e >> 5, k = e & 31;
      As[k][m] = A[(size_t)(mbase + m) * K + k0 + k];
      int kk = e >> 6, n = e & 63;
      Bs[kk][n] = Bt[(size_t)(k0 + kk) * N + nbase + n];
    }
    __syncthreads();
    #pragma unroll
    for (int kk = 0; kk < 32; kk++){
      float av[4], bv[4];
      #pragma unroll
      for (int i = 0; i < 4; i++) av[i] = As[kk][tm*4+i];
      #pragma unroll
      for (int j = 0; j < 4; j++) bv[j] = Bs[kk][tn*4+j];
      #pragma unroll
      for (int i = 0; i < 4; i++)
        #pragma unroll
        for (int j = 0; j < 4; j++)
          acc[i][j] = fmaf(av[i], bv[j], acc[i][j]);
    }
    __syncthreads();
  }
  #pragma unroll
  for (int i = 0; i < 4; i++)
    #pragma unroll
    for (int j = 0; j < 4; j++)
      C[(size_t)(mbase + tm*4 + i) * N + nbase + tn*4 + j] = acc[i][j];
}

// ---- mobius_matvec tail: in-place scale of mx rows by tanh(|mx|/|x| * artanh(|x|)) / |mx|
// one wave per (t,b) row; 3 gates
__global__ void k_nonlin(const float* __restrict__ X, float* __restrict__ D){
  const int row = blockIdx.x;
  const int lane = threadIdx.x;
  const float* x = X + (size_t)row * H_;
  float s = 0.0f;
  for (int k = lane; k < H_; k += 64){ float v = x[k]; s = fmaf(v, v, s); }
  #pragma unroll
  for (int off = 32; off > 0; off >>= 1) s += __shfl_xor(s, off);
  const float xn = fmaxf(sqrtf(s), EPSF);
  const float art = artanh_c(xn);
  float* drow = D + (size_t)row * G3_;
  for (int g = 0; g < 3; g++){
    float* mx = drow + g * H_;
    float s2 = 0.0f;
    for (int k = lane; k < H_; k += 64){ float v = mx[k]; s2 = fmaf(v, v, s2); }
    #pragma unroll
    for (int off = 32; off > 0; off >>= 1) s2 += __shfl_xor(s2, off);
    const float raw = sqrtf(s2);
    const float mn = fmaxf(raw, EPSF);
    const float scale = (raw <= EPSF) ? 0.0f : (tanhf(mn / xn * art) / mn);
    for (int k = lane; k < H_; k += 64) mx[k] *= scale;
  }
}

// ---- sequential scan: one workgroup (256 thr) per batch row
__global__ __launch_bounds__(256) void k_scan(
    const float* __restrict__ D,     // Ux' [T*B][1536], gate cols: r=[0:512) c=[512:1024) z=[1024:1536)
    const float* __restrict__ WzrT,  // [512][1024], cols z|r
    const float* __restrict__ WhhT,  // [512][512] candidate
    const float* __restrict__ bias,  // [3][512] = b_r, b_c, b_z
    const float* __restrict__ h0,    // [64][512]
    float* __restrict__ outbuf,      // [T][64][512]
    float* __restrict__ hlast)       // [64][512]
{
  const int b = blockIdx.x, tid = threadIdx.x;
  __shared__ float h[H_], zbuf[H_], rhs[H_];
  __shared__ float bz[H_], br[H_], bc[H_];
  __shared__ float red[24];
  h[tid]      = h0[b*H_ + tid];
  h[tid+256]  = h0[b*H_ + tid + 256];
  br[tid]     = bias[tid];          br[tid+256] = bias[tid+256];
  bc[tid]     = bias[H_+tid];       bc[tid+256] = bias[H_+tid+256];
  bz[tid]     = bias[2*H_+tid];     bz[tid+256] = bias[2*H_+tid+256];
  __syncthreads();

  const bool isz = (tid < 128);           // phase A: threads 0..127 -> z gate, 128..255 -> r gate
  const int jA = isz ? 4*tid : 4*tid - H_;
  const int jB = 2*tid;

  for (int t = 0; t < T_; t++){
    const float* U = D + (size_t)(t*B_ + b) * G3_;

    // ||h||
    float v1[1] = { h[tid]*h[tid] + h[tid+256]*h[tid+256] };
    block_reduce<1>(v1, red, tid);
    const float h2 = v1[0];
    const float xn = fmaxf(sqrtf(h2), EPSF);
    const float art_h = artanh_c(xn);

    // ---- phase A matmul: mx = h @ [W_hz|W_hr]^T, 4 cols per thread
    float a[4] = {0,0,0,0};
    {
      const float4* wp = (const float4*)WzrT + tid;  // + k*256 per row
      #pragma unroll 8
      for (int k = 0; k < H_; k++){
        const float hk = h[k];
        const float4 w = wp[k*256];
        a[0] = fmaf(w.x, hk, a[0]);
        a[1] = fmaf(w.y, hk, a[1]);
        a[2] = fmaf(w.z, hk, a[2]);
        a[3] = fmaf(w.w, hk, a[3]);
      }
    }
    // per-gate ||mx||
    float v2[2] = {0,0};
    v2[isz?0:1] = a[0]*a[0] + a[1]*a[1] + a[2]*a[2] + a[3]*a[3];
    block_reduce<2>(v2, red, tid);
    const float mraw = sqrtf(isz ? v2[0] : v2[1]);
    const float mn = fmaxf(mraw, EPSF);
    const float alpha = (mraw <= EPSF) ? 0.0f : (tanhf(mn / xn * art_h) / mn);
    float x[4], y[4], bv[4];
    #pragma unroll
    for (int i = 0; i < 4; i++) x[i] = alpha * a[i];
    {
      const float4 y4 = *(const float4*)(U + (isz ? (2*H_ + jA) : jA));
      y[0]=y4.x; y[1]=y4.y; y[2]=y4.z; y[3]=y4.w;
      const float* bp = (isz ? bz : br) + jA;
      #pragma unroll
      for (int i = 0; i < 4; i++) bv[i] = bp[i];
    }
    // t1 = mobius_add(x, y)
    float v6[6] = {0,0,0,0,0,0};
    {
      float px=0, pxy=0, py=0;
      #pragma unroll
      for (int i = 0; i < 4; i++){ px = fmaf(x[i],x[i],px); pxy = fmaf(x[i],y[i],pxy); py = fmaf(y[i],y[i],py); }
      const int o = isz ? 0 : 3;
      v6[o]=px; v6[o+1]=pxy; v6[o+2]=py;
    }
    block_reduce<6>(v6, red, tid);
    const int o = isz ? 0 : 3;
    float t1[4];
    {
      const float X2=v6[o], XY=v6[o+1], Y2=v6[o+2];
      const float cA = 1.0f + 2.0f*XY + Y2, cB = 1.0f - X2;
      const float den = fmaxf(1.0f + 2.0f*XY + X2*Y2, EPSF);
      #pragma unroll
      for (int i = 0; i < 4; i++) t1[i] = (cA*x[i] + cB*y[i]) / den;
    }
    // t2 = mobius_add(t1, bias)
    float v6b[6] = {0,0,0,0,0,0};
    {
      float pt=0, ptb=0, pb=0;
      #pragma unroll
      for (int i = 0; i < 4; i++){ pt = fmaf(t1[i],t1[i],pt); ptb = fmaf(t1[i],bv[i],ptb); pb = fmaf(bv[i],bv[i],pb); }
      v6b[o]=pt; v6b[o+1]=ptb; v6b[o+2]=pb;
    }
    block_reduce<6>(v6b, red, tid);
    float u[4];
    {
      const float Tt2=v6b[o], TB=v6b[o+1], Bb2=v6b[o+2];
      const float cA = 1.0f + 2.0f*TB + Bb2, cB = 1.0f - Tt2;
      const float den = fmaxf(1.0f + 2.0f*TB + Tt2*Bb2, EPSF);
      #pragma unroll
      for (int i = 0; i < 4; i++) u[i] = (cA*t1[i] + cB*bv[i]) / den;
    }
    // gate = sigmoid(logmap0(t2))
    float v2b[2] = {0,0};
    v2b[isz?0:1] = u[0]*u[0] + u[1]*u[1] + u[2]*u[2] + u[3]*u[3];
    block_reduce<2>(v2b, red, tid);
    const float un = fmaxf(sqrtf(isz ? v2b[0] : v2b[1]), EPSF);
    const float lsc = artanh_c(un) / un;
    float g[4], w[4] = {0,0,0,0};
    #pragma unroll
    for (int i = 0; i < 4; i++) g[i] = sigmoidf_(lsc * u[i]);
    if (isz){
      #pragma unroll
      for (int i = 0; i < 4; i++) zbuf[jA+i] = g[i];
    } else {
      #pragma unroll
      for (int i = 0; i < 4; i++) w[i] = g[i] * h[jA+i];  // r .* h
    }
    // rh = mobius_pointwise_mul(r, h)
    float v1b[1] = { w[0]*w[0] + w[1]*w[1] + w[2]*w[2] + w[3]*w[3] };
    block_reduce<1>(v1b, red, tid);
    {
      const float wraw = sqrtf(v1b[0]);
      const float wn = fmaxf(wraw, EPSF);
      const float mu = (wraw <= EPSF) ? 0.0f : (tanhf(wn / xn * art_h) / wn);
      if (!isz){
        #pragma unroll
        for (int i = 0; i < 4; i++) rhs[jA+i] = mu * w[i];
      }
    }
    __syncthreads();

    // ---- phase B matmul: mxc = rh @ W_hh^T, 2 cols per thread
    float c2[2] = {0,0};
    {
      const float2* wp = (const float2*)WhhT + tid;  // + k*256 per row
      #pragma unroll 8
      for (int k = 0; k < H_; k++){
        const float rk = rhs[k];
        const float2 ww = wp[k*256];
        c2[0] = fmaf(ww.x, rk, c2[0]);
        c2[1] = fmaf(ww.y, rk, c2[1]);
      }
    }
    float v2c[2] = { c2[0]*c2[0] + c2[1]*c2[1], rhs[jB]*rhs[jB] + rhs[jB+1]*rhs[jB+1] };
    block_reduce<2>(v2c, red, tid);
    const float craw = sqrtf(v2c[0]);
    const float rhn  = fmaxf(sqrtf(v2c[1]), EPSF);
    const float cmn  = fmaxf(craw, EPSF);
    const float alc  = (craw <= EPSF) ? 0.0f : (tanhf(cmn / rhn * artanh_c(rhn)) / cmn);
    float xc[2] = { alc*c2[0], alc*c2[1] };
    float yc[2], bcv[2];
    { const float2 yy = *(const float2*)(U + H_ + jB); yc[0]=yy.x; yc[1]=yy.y; }
    bcv[0] = bc[jB]; bcv[1] = bc[jB+1];
    // t1c = mobius_add(xc, yc)
    float v3[3] = { xc[0]*xc[0]+xc[1]*xc[1], xc[0]*yc[0]+xc[1]*yc[1], yc[0]*yc[0]+yc[1]*yc[1] };
    block_reduce<3>(v3, red, tid);
    float t1c[2];
    {
      const float X2=v3[0], XY=v3[1], Y2=v3[2];
      const float cA = 1.0f + 2.0f*XY + Y2, cB = 1.0f - X2;
      const float den = fmaxf(1.0f + 2.0f*XY + X2*Y2, EPSF);
      t1c[0] = (cA*xc[0] + cB*yc[0]) / den;
      t1c[1] = (cA*xc[1] + cB*yc[1]) / den;
    }
    // h_tilde = mobius_add(t1c, b_c)
    float v3b[3] = { t1c[0]*t1c[0]+t1c[1]*t1c[1], t1c[0]*bcv[0]+t1c[1]*bcv[1], bcv[0]*bcv[0]+bcv[1]*bcv[1] };
    block_reduce<3>(v3b, red, tid);
    float htl[2];
    {
      const float Tt2=v3b[0], TB=v3b[1], Bb2=v3b[2];
      const float cA = 1.0f + 2.0f*TB + Bb2, cB = 1.0f - Tt2;
      const float den = fmaxf(1.0f + 2.0f*TB + Tt2*Bb2, EPSF);
      htl[0] = (cA*t1c[0] + cB*bcv[0]) / den;
      htl[1] = (cA*t1c[1] + cB*bcv[1]) / den;
    }
    // delta = mobius_add(-h, h_tilde)
    const float hj[2] = { h[jB], h[jB+1] };
    float v2d[2] = { htl[0]*htl[0]+htl[1]*htl[1], hj[0]*htl[0]+hj[1]*htl[1] };
    block_reduce<2>(v2d, red, tid);
    float d[2];
    {
      const float HT2 = v2d[0], XY = -v2d[1];
      const float cA = 1.0f + 2.0f*XY + HT2, cB = 1.0f - h2;
      const float den = fmaxf(1.0f + 2.0f*XY + h2*HT2, EPSF);
      d[0] = (cA*(-hj[0]) + cB*htl[0]) / den;
      d[1] = (cA*(-hj[1]) + cB*htl[1]) / den;
    }
    // zd = mobius_pointwise_mul(z, delta); h_new = mobius_add(h, zd)
    const float zv[2] = { zbuf[jB], zbuf[jB+1] };
    const float w2[2] = { zv[0]*d[0], zv[1]*d[1] };
    float v3c[3] = { d[0]*d[0]+d[1]*d[1], w2[0]*w2[0]+w2[1]*w2[1], hj[0]*w2[0]+hj[1]*w2[1] };
    block_reduce<3>(v3c, red, tid);
    const float dn    = fmaxf(sqrtf(v3c[0]), EPSF);
    const float w2raw = sqrtf(v3c[1]);
    const float w2n   = fmaxf(w2raw, EPSF);
    const float nu    = (w2raw <= EPSF) ? 0.0f : (tanhf(w2n / dn * artanh_c(dn)) / w2n);
    float hnew[2];
    {
      const float Y2 = nu*nu*v3c[1];
      const float XY = nu*v3c[2];
      const float cA = 1.0f + 2.0f*XY + Y2, cB = 1.0f - h2;
      const float den = fmaxf(1.0f + 2.0f*XY + h2*Y2, EPSF);
      hnew[0] = (cA*hj[0] + cB*(nu*w2[0])) / den;
      hnew[1] = (cA*hj[1] + cB*(nu*w2[1])) / den;
    }
    const size_t orow = (size_t)(t*B_ + b) * H_;
    outbuf[orow + jB]     = hnew[0];
    outbuf[orow + jB + 1] = hnew[1];
    h[jB]     = hnew[0];   // safe: all shared reads happened before last block_reduce barrier
    h[jB + 1] = hnew[1];
    __syncthreads();
  }
  hlast[b*H_ + jB]     = h[jB];
  hlast[b*H_ + jB + 1] = h[jB+1];
}

extern "C" void kernel_launch(void* const* d_in, const int* in_sizes, int n_in,
                              void* d_out, int out_size, void* d_ws, size_t ws_size,
                              hipStream_t stream){
  (void)in_sizes; (void)n_in; (void)out_size; (void)ws_size;
  const float* input = (const float*)d_in[0];
  const float* h0    = (const float*)d_in[1];
  const float* wih1  = (const float*)d_in[2];
  const float* wih2  = (const float*)d_in[3];
  const float* whh1  = (const float*)d_in[4];
  const float* whh2  = (const float*)d_in[5];
  const float* bias1 = (const float*)d_in[6];
  const float* bias2 = (const float*)d_in[7];
  float* out = (float*)d_out;

  // ws layout (floats): WihT 786432 | WzrT 524288 | WhhT 262144 | Ux 25165824  (~107 MB)
  float* A_   = (float*)d_ws;
  float* Bzr  = A_  + 786432;
  float* Chh  = Bzr + 524288;
  float* Dbuf = Chh + 262144;

  float* out1 = out;            // layer-1 outputs staged in out2 region (consumed before overwrite)
  float* ht   = out + (size_t)T_ * B_ * H_;   // [2][64][512]

  // ---- layer 1
  k_prep_ih<<<3072, 256, 0, stream>>>(wih1, A_);
  k_gemm<<<dim3(256, 24), 256, 0, stream>>>(input, A_, Dbuf);
  k_nonlin<<<T_*B_, 64, 0, stream>>>(input, Dbuf);
  k_prep_hh<<<3072, 256, 0, stream>>>(whh1, Bzr, Chh);
  k_scan<<<B_, 256, 0, stream>>>(Dbuf, Bzr, Chh, bias1, h0, out1, ht);

  // ---- layer 2
  k_prep_ih<<<3072, 256, 0, stream>>>(wih2, A_);
  k_gemm<<<dim3(256, 24), 256, 0, stream>>>(out1, A_, Dbuf);
  k_nonlin<<<T_*B_, 64, 0, stream>>>(out1, Dbuf);
  k_prep_hh<<<3072, 256, 0, stream>>>(whh2, Bzr, Chh);
  k_scan<<<B_, 256, 0, stream>>>(Dbuf, Bzr, Chh, bias2, h0 + B_*H_, out, ht + B_*H_);
}

// Round 2
// 16608.426 us; speedup vs baseline: 1.1647x; 1.1647x over previous
//
#include <hip/hip_runtime.h>
#include <hip/hip_fp16.h>
#include <math.h>
#include <stdint.h>

// MobiusGRU T=256 B=64 D=H=512, 2 layers.
// R2 changes vs R1: scan uses 1024 thr/WG (4 waves/SIMD latency hiding),
// f16 weights (halve L2 stream), and analytic mobius-dot fusion:
// 11 block-reduces/step -> 4 (reduce<11>, reduce<1>, reduce<8>, reduce<3>).

#define T_  256
#define B_  64
#define H_  512
#define G3_ 1536
#define EPSF 1e-15f
#define CLIPF (1.0f - 1e-5f)

__device__ __forceinline__ float artanh_c(float x){
  x = fminf(fmaxf(x, -CLIPF), CLIPF);
  return 0.5f * logf((1.0f + x) / (1.0f - x));
}
__device__ __forceinline__ float sigmoidf_(float x){ return 1.0f/(1.0f+expf(-x)); }

// block reduction over 1024 threads (16 waves)
template<int NS>
__device__ __forceinline__ void block_reduce(float (&v)[NS], float* red, int tid){
  #pragma unroll
  for (int off = 32; off > 0; off >>= 1)
    #pragma unroll
    for (int s = 0; s < NS; s++) v[s] += __shfl_xor(v[s], off);
  const int wave = tid >> 6;
  if ((tid & 63) == 0)
    #pragma unroll
    for (int s = 0; s < NS; s++) red[wave*NS + s] = v[s];
  __syncthreads();
  #pragma unroll
  for (int s = 0; s < NS; s++){
    float acc = 0.f;
    #pragma unroll
    for (int w = 0; w < 16; w++) acc += red[w*NS + s];
    v[s] = acc;
  }
  __syncthreads();
}

// ---- transpose weight_ih [1536][512] -> WihT [512][1536]
__global__ void k_prep_ih(const float* __restrict__ Wih, float* __restrict__ WihT){
  int i = blockIdx.x * blockDim.x + threadIdx.x;
  if (i >= H_ * G3_) return;
  int k = i / G3_, n = i % G3_;
  WihT[i] = Wih[n * H_ + k];
}

// ---- weight_hh [1536][512] -> f16-packed WzrH [256 k2][1024 cols z|r], WhhH [256 k2][512]
// weight_hh row split: [0:512)=W_hr, [512:1024)=W_hh(candidate), [1024:1536)=W_hz
__global__ void k_prep_hhH(const float* __restrict__ Whh, __half2* __restrict__ WzrH,
                           __half2* __restrict__ WhhH){
  int i = blockIdx.x * blockDim.x + threadIdx.x;   // 393216 total
  if (i < 256*1024){
    int k2 = i >> 10, col = i & 1023;
    int row = (col < 512) ? (1024 + col) : (col - 512);   // z | r
    WzrH[i] = __halves2half2(__float2half_rn(Whh[row*H_ + 2*k2]),
                             __float2half_rn(Whh[row*H_ + 2*k2 + 1]));
  } else {
    int i2 = i - 256*1024;
    int k2 = i2 >> 9, col = i2 & 511;
    WhhH[i2] = __halves2half2(__float2half_rn(Whh[(H_ + col)*H_ + 2*k2]),
                              __float2half_rn(Whh[(H_ + col)*H_ + 2*k2 + 1]));
  }
}

// ---- tiled f32 GEMM: C[16384][1536] = A[16384][512] * Bt[512][1536]
__global__ __launch_bounds__(256) void k_gemm(const float* __restrict__ A,
                                              const float* __restrict__ Bt,
                                              float* __restrict__ C){
  const int N = G3_, K = H_;
  const int mbase = blockIdx.x * 64, nbase = blockIdx.y * 64;
  __shared__ float As[32][65];
  __shared__ float Bs[32][65];
  const int tid = threadIdx.x;
  const int tm = tid >> 4, tn = tid & 15;
  float acc[4][4] = {};
  for (int k0 = 0; k0 < K; k0 += 32){
    #pragma unroll
    for (int i = 0; i < 8; i++){
      int e = tid + 256*i;
      int m = e >> 5, k = e & 31;
      As[k][m] = A[(size_t)(mbase + m) * K + k0 + k];
      int kk = e >> 6, n = e & 63;
      Bs[kk][n] = Bt[(size_t)(k0 + kk) * N + nbase + n];
    }
    __syncthreads();
    #pragma unroll
    for (int kk = 0; kk < 32; kk++){
      float av[4], bv[4];
      #pragma unroll
      for (int i = 0; i < 4; i++) av[i] = As[kk][tm*4+i];
      #pragma unroll
      for (int j = 0; j < 4; j++) bv[j] = Bs[kk][tn*4+j];
      #pragma unroll
      for (int i = 0; i < 4; i++)
        #pragma unroll
        for (int j = 0; j < 4; j++)
          acc[i][j] = fmaf(av[i], bv[j], acc[i][j]);
    }
    __syncthreads();
  }
  #pragma unroll
  for (int i = 0; i < 4; i++)
    #pragma unroll
    for (int j = 0; j < 4; j++)
      C[(size_t)(mbase + tm*4 + i) * N + nbase + tn*4 + j] = acc[i][j];
}

// ---- mobius_matvec tail on Ux rows
__global__ void k_nonlin(const float* __restrict__ X, float* __restrict__ D){
  const int row = blockIdx.x;
  const int lane = threadIdx.x;
  const float* x = X + (size_t)row * H_;
  float s = 0.0f;
  for (int k = lane; k < H_; k += 64){ float v = x[k]; s = fmaf(v, v, s); }
  #pragma unroll
  for (int off = 32; off > 0; off >>= 1) s += __shfl_xor(s, off);
  const float xn = fmaxf(sqrtf(s), EPSF);
  const float art = artanh_c(xn);
  float* drow = D + (size_t)row * G3_;
  for (int g = 0; g < 3; g++){
    float* mx = drow + g * H_;
    float s2 = 0.0f;
    for (int k = lane; k < H_; k += 64){ float v = mx[k]; s2 = fmaf(v, v, s2); }
    #pragma unroll
    for (int off = 32; off > 0; off >>= 1) s2 += __shfl_xor(s2, off);
    const float raw = sqrtf(s2);
    const float mn = fmaxf(raw, EPSF);
    const float scale = (raw <= EPSF) ? 0.0f : (tanhf(mn / xn * art) / mn);
    for (int k = lane; k < H_; k += 64) mx[k] *= scale;
  }
}

// ---- sequential scan: 1 WG (1024 thr) per batch row
__global__ __launch_bounds__(1024, 1) void k_scan(
    const float* __restrict__ D,        // Ux' [T*B][1536]: r|c|z col blocks
    const __half2* __restrict__ WzrH,   // [256 k2][1024 cols] z|r
    const __half2* __restrict__ WhhH,   // [256 k2][512 cols] candidate
    const float* __restrict__ bias,     // [3][512] = b_r, b_c, b_z
    const float* __restrict__ h0,
    float* __restrict__ outbuf,         // [T][64][512]
    float* __restrict__ hlast)
{
  const int b = blockIdx.x, tid = threadIdx.x;
  __shared__ float h[H_], zbuf[H_], rhs[H_];
  __shared__ float ph[1024];
  __shared__ float red[176];
  const bool isz = tid < 512;           // z-half owns z cols; r-half owns r cols
  const bool lolane = tid < 512;
  const int j = isz ? tid : tid - 512;
  if (lolane) h[tid] = h0[b*H_ + tid];
  const float bval = bias[isz ? (2*H_ + j) : j];    // my gate's bias element
  const float bcj  = lolane ? bias[H_ + tid] : 0.f; // candidate bias element
  // bias norms (loop-invariant)
  float vb[3] = { isz ? bval*bval : 0.f, isz ? 0.f : bval*bval, bcj*bcj };
  block_reduce<3>(vb, red, tid);
  const float B2z = vb[0], B2r = vb[1], BC2 = vb[2];
  const float B2 = isz ? B2z : B2r;

  const int colB = tid & 511, halfk = tid >> 9;
  const float* Urow0 = D + (size_t)b * G3_;

  for (int t = 0; t < T_; t++){
    const float* U = Urow0 + (size_t)t * (B_ * G3_);

    // ---- phase A: a_col = sum_k W[k][col] h[k], col = tid (z|r)
    float a = 0.f;
    {
      const __half2* wp = WzrH + tid;
      #pragma unroll 8
      for (int k2 = 0; k2 < 256; k2++){
        const __half2 w = wp[k2*1024];
        a = fmaf(__low2float(w), h[2*k2], fmaf(__high2float(w), h[2*k2+1], a));
      }
    }
    const float y = U[isz ? (2*H_ + j) : j];
    const float hv = lolane ? h[tid] : 0.f;
    // R1: {h2 | per-gate a2, ay, y2, ab, yb}
    float v1[11];
    #pragma unroll
    for (int s = 0; s < 11; s++) v1[s] = 0.f;
    v1[0] = hv*hv;
    {
      const int o = isz ? 1 : 6;
      v1[o+0] = a*a; v1[o+1] = a*y; v1[o+2] = y*y; v1[o+3] = a*bval; v1[o+4] = y*bval;
    }
    block_reduce<11>(v1, red, tid);
    const float H2 = v1[0];
    const int o = isz ? 1 : 6;
    const float A2 = v1[o], AY = v1[o+1], Yy2 = v1[o+2], AB = v1[o+3], YB = v1[o+4];
    const float xn = fmaxf(sqrtf(H2), EPSF);
    const float art_h = artanh_c(xn);
    const float mraw = sqrtf(A2);
    const float mnc = fmaxf(mraw, EPSF);
    const float alpha = (mraw <= EPSF) ? 0.f : (tanhf(mnc/xn*art_h)/mnc);
    // t1 = (alpha*a) (+) y ; t2 = t1 (+) b ; gate = sigmoid(artanh(|t2|)/|t2| * t2)
    const float X2 = alpha*alpha*A2, XY = alpha*AY, XB = alpha*AB;
    const float cA1 = 1.f + 2.f*XY + Yy2, cB1 = 1.f - X2;
    const float den1 = fmaxf(1.f + 2.f*XY + X2*Yy2, EPSF), id1 = 1.f/den1;
    const float T2 = fmaxf((cA1*cA1*X2 + 2.f*cA1*cB1*XY + cB1*cB1*Yy2)*id1*id1, 0.f);
    const float TB = (cA1*XB + cB1*YB)*id1;
    const float cA2 = 1.f + 2.f*TB + B2, cB2 = 1.f - T2;
    const float den2 = fmaxf(1.f + 2.f*TB + T2*B2, EPSF), id2 = 1.f/den2;
    const float U2 = fmaxf((cA2*cA2*T2 + 2.f*cA2*cB2*TB + cB2*cB2*B2)*id2*id2, 0.f);
    const float un = fmaxf(sqrtf(U2), EPSF);
    const float lsc = artanh_c(un)/un;
    const float t1el = (cA1*(alpha*a) + cB1*y)*id1;
    const float uel  = (cA2*t1el + cB2*bval)*id2;
    const float g = sigmoidf_(lsc*uel);
    float wv = 0.f;
    if (isz) zbuf[j] = g; else wv = g*h[j];
    // R2: ||r.*h||^2
    float v2[1] = { wv*wv };
    block_reduce<1>(v2, red, tid);
    const float W2 = v2[0];
    const float wraw = sqrtf(W2);
    const float wn = fmaxf(wraw, EPSF);
    const float mu = (wraw <= EPSF) ? 0.f : (tanhf(wn/xn*art_h)/wn);
    if (!isz) rhs[j] = mu*wv;
    const float rhn = fmaxf(mu*wraw, EPSF);   // ||rh|| analytic
    __syncthreads();                          // rhs, zbuf visible

    // ---- phase B: c_col = sum_k Whh[k][col] rh[k], split-k x2
    float cpart = 0.f;
    {
      const __half2* wp = WhhH + (size_t)(halfk*128)*512 + colB;
      #pragma unroll 8
      for (int k2i = 0; k2i < 128; k2i++){
        const __half2 w = wp[k2i*512];
        const int kk = 2*(halfk*128 + k2i);
        cpart = fmaf(__low2float(w), rhs[kk], fmaf(__high2float(w), rhs[kk+1], cpart));
      }
    }
    ph[tid] = cpart;
    __syncthreads();
    float cel = 0.f, ycel = 0.f, hj = 0.f;
    if (lolane){
      cel  = ph[tid] + ph[tid + 512];
      ycel = U[H_ + tid];
      hj   = h[tid];
    }
    // R3: {c2, c.y, y2, c.bc, y.bc, h.c, h.y, h.bc}
    float v8[8];
    v8[0]=cel*cel; v8[1]=cel*ycel; v8[2]=ycel*ycel; v8[3]=cel*bcj;
    v8[4]=ycel*bcj; v8[5]=hj*cel; v8[6]=hj*ycel; v8[7]=hj*bcj;
    block_reduce<8>(v8, red, tid);
    const float C2=v8[0], CY=v8[1], Y2c=v8[2], CB=v8[3], YBc=v8[4], HC=v8[5], HYd=v8[6], HBd=v8[7];
    const float craw = sqrtf(C2);
    const float cmn2 = fmaxf(craw, EPSF);
    const float alc = (craw <= EPSF) ? 0.f : (tanhf(cmn2/rhn*artanh_c(rhn))/cmn2);
    const float X2c = alc*alc*C2, XYc = alc*CY, XBc = alc*CB, HXc = alc*HC;
    const float cA1c = 1.f + 2.f*XYc + Y2c, cB1c = 1.f - X2c;
    const float den1c = fmaxf(1.f + 2.f*XYc + X2c*Y2c, EPSF), id1c = 1.f/den1c;
    const float T2c = fmaxf((cA1c*cA1c*X2c + 2.f*cA1c*cB1c*XYc + cB1c*cB1c*Y2c)*id1c*id1c, 0.f);
    const float TBc = (cA1c*XBc + cB1c*YBc)*id1c;
    const float HT1 = (cA1c*HXc + cB1c*HYd)*id1c;
    const float cA2c = 1.f + 2.f*TBc + BC2, cB2c = 1.f - T2c;
    const float den2c = fmaxf(1.f + 2.f*TBc + T2c*BC2, EPSF), id2c = 1.f/den2c;
    const float HTL2 = fmaxf((cA2c*cA2c*T2c + 2.f*cA2c*cB2c*TBc + cB2c*cB2c*BC2)*id2c*id2c, 0.f);
    const float HHTL = (cA2c*HT1 + cB2c*HBd)*id2c;
    // delta = (-h) (+) h_tilde
    const float cAd = 1.f - 2.f*HHTL + HTL2, cBd = 1.f - H2;
    const float dend = fmaxf(1.f - 2.f*HHTL + H2*HTL2, EPSF), idd = 1.f/dend;
    const float t1cel = (cA1c*(alc*cel) + cB1c*ycel)*id1c;
    const float htlel = (cA2c*t1cel + cB2c*bcj)*id2c;
    const float del = (cAd*(-hj) + cBd*htlel)*idd;
    const float zv = lolane ? zbuf[tid] : 0.f;
    const float w2el = zv*del;
    // R4: {|delta|^2, |z.*delta|^2, h.(z.*delta)}
    float v3[3] = { del*del, w2el*w2el, hj*w2el };
    block_reduce<3>(v3, red, tid);
    const float D2 = v3[0], W22 = v3[1], HW = v3[2];
    const float dn = fmaxf(sqrtf(D2), EPSF);
    const float w2raw = sqrtf(W22);
    const float w2n = fmaxf(w2raw, EPSF);
    const float nu = (w2raw <= EPSF) ? 0.f : (tanhf(w2n/dn*artanh_c(dn))/w2n);
    const float Y2f = nu*nu*W22, XYf = nu*HW;
    const float cAf = 1.f + 2.f*XYf + Y2f, cBf = 1.f - H2;
    const float denf = fmaxf(1.f + 2.f*XYf + H2*Y2f, EPSF), idf = 1.f/denf;
    if (lolane){
      const float hnew = (cAf*hj + cBf*(nu*w2el))*idf;
      outbuf[(size_t)(t*B_ + b)*H_ + tid] = hnew;
      h[tid] = hnew;
    }
    __syncthreads();
  }
  if (lolane) hlast[b*H_ + tid] = h[tid];
}

extern "C" void kernel_launch(void* const* d_in, const int* in_sizes, int n_in,
                              void* d_out, int out_size, void* d_ws, size_t ws_size,
                              hipStream_t stream){
  (void)in_sizes; (void)n_in; (void)out_size; (void)ws_size;
  const float* input = (const float*)d_in[0];
  const float* h0    = (const float*)d_in[1];
  const float* wih1  = (const float*)d_in[2];
  const float* wih2  = (const float*)d_in[3];
  const float* whh1  = (const float*)d_in[4];
  const float* whh2  = (const float*)d_in[5];
  const float* bias1 = (const float*)d_in[6];
  const float* bias2 = (const float*)d_in[7];
  float* out = (float*)d_out;

  // ws: WihT 786432 f | Dbuf 25165824 f | WzrH 262144 h2 | WhhH 131072 h2 (~105 MB)
  float* A_   = (float*)d_ws;
  float* Dbuf = A_ + 786432;
  __half2* WzrH = (__half2*)(Dbuf + 25165824);
  __half2* WhhH = WzrH + 262144;

  float* out1 = out;                           // staged; consumed before scan-2 overwrites
  float* ht   = out + (size_t)T_ * B_ * H_;

  // layer 1
  k_prep_ih<<<3072, 256, 0, stream>>>(wih1, A_);
  k_gemm<<<dim3(256, 24), 256, 0, stream>>>(input, A_, Dbuf);
  k_nonlin<<<T_*B_, 64, 0, stream>>>(input, Dbuf);
  k_prep_hhH<<<1536, 256, 0, stream>>>(whh1, WzrH, WhhH);
  k_scan<<<B_, 1024, 0, stream>>>(Dbuf, WzrH, WhhH, bias1, h0, out1, ht);

  // layer 2
  k_prep_ih<<<3072, 256, 0, stream>>>(wih2, A_);
  k_gemm<<<dim3(256, 24), 256, 0, stream>>>(out1, A_, Dbuf);
  k_nonlin<<<T_*B_, 64, 0, stream>>>(out1, Dbuf);
  k_prep_hhH<<<1536, 256, 0, stream>>>(whh2, WzrH, WhhH);
  k_scan<<<B_, 1024, 0, stream>>>(Dbuf, WzrH, WhhH, bias2, h0 + B_*H_, out, ht + B_*H_);
}

// Round 3
// 16500.322 us; speedup vs baseline: 1.1723x; 1.0066x over previous
//
#include <hip/hip_runtime.h>
#include <hip/hip_fp16.h>
#include <math.h>
#include <stdint.h>

// MobiusGRU T=256 B=64 D=H=512, 2 layers.
// R3 vs R2: kill scratch spills in k_scan (WRITE_SIZE 941MB was spill traffic).
//  - 6-slot split-half reduce instead of 11-slot (each half reduces own gate dots)
//  - phase-B reduces on waves 0-7 only
//  - weights packed 4-k-wide ({half2,half2} = 8B) -> dwordx2 + ds_read_b128(h)
//  - 7 barriers/step

#define T_  256
#define B_  64
#define H_  512
#define G3_ 1536
#define EPSF 1e-15f
#define CLIPF (1.0f - 1e-5f)

struct __align__(8) h2x2 { __half2 a, b; };

__device__ __forceinline__ float artanh_c(float x){
  x = fminf(fmaxf(x, -CLIPF), CLIPF);
  return 0.5f * logf((1.0f + x) / (1.0f - x));
}
__device__ __forceinline__ float sigmoidf_(float x){ return 1.0f/(1.0f+expf(-x)); }

// shuffle-reduce NS values across the wave; lane0 stores to red[wave*NS+s]
template<int NS>
__device__ __forceinline__ void wave_reduce_store(float (&v)[NS], float* red, int tid){
  #pragma unroll
  for (int off = 32; off > 0; off >>= 1)
    #pragma unroll
    for (int s = 0; s < NS; s++) v[s] += __shfl_xor(v[s], off);
  if ((tid & 63) == 0)
    #pragma unroll
    for (int s = 0; s < NS; s++) red[(tid >> 6)*NS + s] = v[s];
}

// ---- transpose weight_ih [1536][512] -> WihT [512][1536]
__global__ void k_prep_ih(const float* __restrict__ Wih, float* __restrict__ WihT){
  int i = blockIdx.x * blockDim.x + threadIdx.x;
  if (i >= H_ * G3_) return;
  int k = i / G3_, n = i % G3_;
  WihT[i] = Wih[n * H_ + k];
}

// ---- weight_hh -> packed f16, 4-k-wide: Wzr4[k4][1024 cols z|r], Whc4[k4][512]
// weight_hh row split: [0:512)=W_hr, [512:1024)=W_hh(cand), [1024:1536)=W_hz
__global__ void k_prep_hh4(const float* __restrict__ Whh, h2x2* __restrict__ Wzr4,
                           h2x2* __restrict__ Whc4){
  int i = blockIdx.x * blockDim.x + threadIdx.x;   // 196608 total
  if (i < 128*1024){
    int k4 = i >> 10, col = i & 1023;
    int row = (col < 512) ? (1024 + col) : (col - 512);   // z | r
    const float* s = Whh + row*H_ + 4*k4;
    h2x2 w;
    w.a = __halves2half2(__float2half_rn(s[0]), __float2half_rn(s[1]));
    w.b = __halves2half2(__float2half_rn(s[2]), __float2half_rn(s[3]));
    Wzr4[i] = w;
  } else {
    int i2 = i - 128*1024;
    if (i2 < 128*512){
      int k4 = i2 >> 9, col = i2 & 511;
      const float* s = Whh + (H_ + col)*H_ + 4*k4;
      h2x2 w;
      w.a = __halves2half2(__float2half_rn(s[0]), __float2half_rn(s[1]));
      w.b = __halves2half2(__float2half_rn(s[2]), __float2half_rn(s[3]));
      Whc4[i2] = w;
    }
  }
}

// ---- tiled f32 GEMM: C[16384][1536] = A[16384][512] * Bt[512][1536]
__global__ __launch_bounds__(256) void k_gemm(const float* __restrict__ A,
                                              const float* __restrict__ Bt,
                                              float* __restrict__ C){
  const int N = G3_, K = H_;
  const int mbase = blockIdx.x * 64, nbase = blockIdx.y * 64;
  __shared__ float As[32][65];
  __shared__ float Bs[32][65];
  const int tid = threadIdx.x;
  const int tm = tid >> 4, tn = tid & 15;
  float acc[4][4] = {};
  for (int k0 = 0; k0 < K; k0 += 32){
    #pragma unroll
    for (int i = 0; i < 8; i++){
      int e = tid + 256*i;
      int m = e >> 5, k = e & 31;
      As[k][m] = A[(size_t)(mbase + m) * K + k0 + k];
      int kk = e >> 6, n = e & 63;
      Bs[kk][n] = Bt[(size_t)(k0 + kk) * N + nbase + n];
    }
    __syncthreads();
    #pragma unroll
    for (int kk = 0; kk < 32; kk++){
      float av[4], bv[4];
      #pragma unroll
      for (int i = 0; i < 4; i++) av[i] = As[kk][tm*4+i];
      #pragma unroll
      for (int j = 0; j < 4; j++) bv[j] = Bs[kk][tn*4+j];
      #pragma unroll
      for (int i = 0; i < 4; i++)
        #pragma unroll
        for (int j = 0; j < 4; j++)
          acc[i][j] = fmaf(av[i], bv[j], acc[i][j]);
    }
    __syncthreads();
  }
  #pragma unroll
  for (int i = 0; i < 4; i++)
    #pragma unroll
    for (int j = 0; j < 4; j++)
      C[(size_t)(mbase + tm*4 + i) * N + nbase + tn*4 + j] = acc[i][j];
}

// ---- mobius_matvec tail on Ux rows
__global__ void k_nonlin(const float* __restrict__ X, float* __restrict__ D){
  const int row = blockIdx.x;
  const int lane = threadIdx.x;
  const float* x = X + (size_t)row * H_;
  float s = 0.0f;
  for (int k = lane; k < H_; k += 64){ float v = x[k]; s = fmaf(v, v, s); }
  #pragma unroll
  for (int off = 32; off > 0; off >>= 1) s += __shfl_xor(s, off);
  const float xn = fmaxf(sqrtf(s), EPSF);
  const float art = artanh_c(xn);
  float* drow = D + (size_t)row * G3_;
  for (int g = 0; g < 3; g++){
    float* mx = drow + g * H_;
    float s2 = 0.0f;
    for (int k = lane; k < H_; k += 64){ float v = mx[k]; s2 = fmaf(v, v, s2); }
    #pragma unroll
    for (int off = 32; off > 0; off >>= 1) s2 += __shfl_xor(s2, off);
    const float raw = sqrtf(s2);
    const float mn = fmaxf(raw, EPSF);
    const float scale = (raw <= EPSF) ? 0.0f : (tanhf(mn / xn * art) / mn);
    for (int k = lane; k < H_; k += 64) mx[k] *= scale;
  }
}

// ---- sequential scan: 1 WG (1024 thr) per batch row
// red regions: red1 [0,96) 6-slot; red2 [96,112) 1-slot; red3 [112,176) 8-slot(8w); red4 [176,200) 3-slot(8w)
__global__ __launch_bounds__(1024, 1) void k_scan(
    const float* __restrict__ D,        // Ux' [T*B][1536]: r|c|z col blocks
    const h2x2* __restrict__ Wzr4,      // [128 k4][1024 cols] z|r
    const h2x2* __restrict__ Whc4,      // [128 k4][512 cols] candidate
    const float* __restrict__ bias,     // [3][512] = b_r, b_c, b_z
    const float* __restrict__ h0,
    float* __restrict__ outbuf,         // [T][64][512]
    float* __restrict__ hlast)
{
  const int b = blockIdx.x, tid = threadIdx.x;
  __shared__ __align__(16) float h[H_];
  __shared__ __align__(16) float rhs[H_];
  __shared__ float zbuf[H_];
  __shared__ float ph[1024];
  __shared__ float red[200];
  const int wave = tid >> 6;
  const bool isz = tid < 512;          // also "lolane"
  const int j = isz ? tid : tid - 512;
  if (isz) h[tid] = h0[b*H_ + tid];
  const float bval = bias[isz ? (2*H_ + j) : j];     // own gate bias elem (z|r)
  const float bcj  = isz ? bias[H_ + tid] : 0.f;     // candidate bias elem
  // loop-invariant bias norms
  float B2, BC2;
  {
    float vb[2] = { bval*bval, bcj*bcj };
    wave_reduce_store<2>(vb, red, tid);
    __syncthreads();
    float bz = 0.f;
    {
      const int wb = isz ? 0 : 8;
      for (int w = 0; w < 8; w++) bz += red[(wb + w)*2 + 0];
    }
    B2 = bz;
    float bc2 = 0.f;
    for (int w = 0; w < 8; w++) bc2 += red[w*2 + 1];
    BC2 = bc2;
    __syncthreads();
  }

  const int colB = tid & 511, halfk = tid >> 9;
  const h2x2* wpA = Wzr4 + tid;
  const h2x2* wpB = Whc4 + (size_t)(halfk * 64) * 512 + colB;
  const float* Urow0 = D + (size_t)b * G3_;

  for (int t = 0; t < T_; t++){
    const float* U = Urow0 + (size_t)t * (B_ * G3_);

    // ---- phase A: a = sum_k W[k][tid] h[k]  (col tid of z|r)
    float a = 0.f;
    {
      const float4* h4 = (const float4*)h;
      #pragma unroll 4
      for (int k4 = 0; k4 < 128; k4++){
        const h2x2 w = wpA[k4*1024];
        const float4 hh = h4[k4];
        a = fmaf(__low2float(w.a),  hh.x, a);
        a = fmaf(__high2float(w.a), hh.y, a);
        a = fmaf(__low2float(w.b),  hh.z, a);
        a = fmaf(__high2float(w.b), hh.w, a);
      }
    }
    const float y = U[isz ? (2*H_ + j) : j];
    const float hv = isz ? h[tid] : 0.f;
    // R1: slots {h2, a2, ay, y2, ab, yb} — gate dots reduced per half
    float v6[6] = { hv*hv, a*a, a*y, y*y, a*bval, y*bval };
    wave_reduce_store<6>(v6, red, tid);
    __syncthreads();   // bar1
    float H2 = 0.f, A2 = 0.f, AY = 0.f, Yy2 = 0.f, AB = 0.f, YB = 0.f;
    {
      for (int w = 0; w < 16; w++) H2 += red[w*6 + 0];
      const int wb = isz ? 0 : 8;
      for (int w = 0; w < 8; w++){
        const float* r = red + (wb + w)*6;
        A2 += r[1]; AY += r[2]; Yy2 += r[3]; AB += r[4]; YB += r[5];
      }
    }
    const float xn = fmaxf(sqrtf(H2), EPSF);
    const float art_h = artanh_c(xn);
    const float mraw = sqrtf(A2);
    const float mnc = fmaxf(mraw, EPSF);
    const float alpha = (mraw <= EPSF) ? 0.f : (tanhf(mnc/xn*art_h)/mnc);
    // t1 = (alpha*a) (+) y ; t2 = t1 (+) b ; gate = sigmoid(artanh(|t2|)/|t2| * t2el)
    const float X2 = alpha*alpha*A2, XY = alpha*AY, XB = alpha*AB;
    const float cA1 = 1.f + 2.f*XY + Yy2, cB1 = 1.f - X2;
    const float den1 = fmaxf(1.f + 2.f*XY + X2*Yy2, EPSF), id1 = 1.f/den1;
    const float T2 = fmaxf((cA1*cA1*X2 + 2.f*cA1*cB1*XY + cB1*cB1*Yy2)*id1*id1, 0.f);
    const float TB = (cA1*XB + cB1*YB)*id1;
    const float cA2 = 1.f + 2.f*TB + B2, cB2 = 1.f - T2;
    const float den2 = fmaxf(1.f + 2.f*TB + T2*B2, EPSF), id2 = 1.f/den2;
    const float U2 = fmaxf((cA2*cA2*T2 + 2.f*cA2*cB2*TB + cB2*cB2*B2)*id2*id2, 0.f);
    const float un = fmaxf(sqrtf(U2), EPSF);
    const float lsc = artanh_c(un)/un;
    const float t1el = (cA1*(alpha*a) + cB1*y)*id1;
    const float uel  = (cA2*t1el + cB2*bval)*id2;
    const float g = sigmoidf_(lsc*uel);
    float wv = 0.f;
    if (isz) zbuf[j] = g; else wv = g*h[j];
    // R2: ||r.*h||^2 (r half only carries data)
    float v1[1] = { wv*wv };
    wave_reduce_store<1>(v1, red + 96, tid);
    __syncthreads();   // bar2
    float W2 = 0.f;
    for (int w = 8; w < 16; w++) W2 += red[96 + w];
    const float wraw = sqrtf(W2);
    const float wn = fmaxf(wraw, EPSF);
    const float mu = (wraw <= EPSF) ? 0.f : (tanhf(wn/xn*art_h)/wn);
    if (!isz) rhs[j] = mu*wv;
    const float rhn = fmaxf(mu*wraw, EPSF);
    __syncthreads();   // bar3: rhs, zbuf visible

    // ---- phase B: c_col = sum_k Whc[k][colB] rh[k], split-k x2
    float cpart = 0.f;
    {
      const float4* r4 = (const float4*)rhs + halfk*64;
      #pragma unroll 4
      for (int k4i = 0; k4i < 64; k4i++){
        const h2x2 w = wpB[k4i*512];
        const float4 rr = r4[k4i];
        cpart = fmaf(__low2float(w.a),  rr.x, cpart);
        cpart = fmaf(__high2float(w.a), rr.y, cpart);
        cpart = fmaf(__low2float(w.b),  rr.z, cpart);
        cpart = fmaf(__high2float(w.b), rr.w, cpart);
      }
    }
    ph[tid] = cpart;
    __syncthreads();   // bar4
    if (wave < 8){
      const float cel  = ph[tid] + ph[tid + 512];
      const float ycel = U[H_ + tid];
      const float hj   = h[tid];
      // R3: {c2, cy, y2, cb, yb, hc, hy, hb}
      float v8[8];
      v8[0]=cel*cel; v8[1]=cel*ycel; v8[2]=ycel*ycel; v8[3]=cel*bcj;
      v8[4]=ycel*bcj; v8[5]=hj*cel; v8[6]=hj*ycel; v8[7]=hj*bcj;
      wave_reduce_store<8>(v8, red + 112, tid);
      __syncthreads(); // bar5
      float C2=0,CY=0,Y2c=0,CB=0,YBc=0,HC=0,HYd=0,HBd=0;
      for (int w = 0; w < 8; w++){
        const float* r = red + 112 + w*8;
        C2+=r[0]; CY+=r[1]; Y2c+=r[2]; CB+=r[3]; YBc+=r[4]; HC+=r[5]; HYd+=r[6]; HBd+=r[7];
      }
      const float craw = sqrtf(C2);
      const float cmn2 = fmaxf(craw, EPSF);
      const float alc = (craw <= EPSF) ? 0.f : (tanhf(cmn2/rhn*artanh_c(rhn))/cmn2);
      const float X2c = alc*alc*C2, XYc = alc*CY, XBc = alc*CB, HXc = alc*HC;
      const float cA1c = 1.f + 2.f*XYc + Y2c, cB1c = 1.f - X2c;
      const float den1c = fmaxf(1.f + 2.f*XYc + X2c*Y2c, EPSF), id1c = 1.f/den1c;
      const float T2c = fmaxf((cA1c*cA1c*X2c + 2.f*cA1c*cB1c*XYc + cB1c*cB1c*Y2c)*id1c*id1c, 0.f);
      const float TBc = (cA1c*XBc + cB1c*YBc)*id1c;
      const float HT1 = (cA1c*HXc + cB1c*HYd)*id1c;
      const float cA2c = 1.f + 2.f*TBc + BC2, cB2c = 1.f - T2c;
      const float den2c = fmaxf(1.f + 2.f*TBc + T2c*BC2, EPSF), id2c = 1.f/den2c;
      const float HTL2 = fmaxf((cA2c*cA2c*T2c + 2.f*cA2c*cB2c*TBc + cB2c*cB2c*BC2)*id2c*id2c, 0.f);
      const float HHTL = (cA2c*HT1 + cB2c*HBd)*id2c;
      const float cAd = 1.f - 2.f*HHTL + HTL2, cBd = 1.f - H2;
      const float dend = fmaxf(1.f - 2.f*HHTL + H2*HTL2, EPSF), idd = 1.f/dend;
      const float t1cel = (cA1c*(alc*cel) + cB1c*ycel)*id1c;
      const float htlel = (cA2c*t1cel + cB2c*bcj)*id2c;
      const float del = (cAd*(-hj) + cBd*htlel)*idd;
      const float zv = zbuf[tid];
      const float w2el = zv*del;
      // R4: {|delta|^2, |z.*delta|^2, h.(z.*delta)}
      float v3[3] = { del*del, w2el*w2el, hj*w2el };
      wave_reduce_store<3>(v3, red + 176, tid);
      __syncthreads(); // bar6
      float D2=0, W22=0, HW=0;
      for (int w = 0; w < 8; w++){
        const float* r = red + 176 + w*3;
        D2+=r[0]; W22+=r[1]; HW+=r[2];
      }
      const float dn = fmaxf(sqrtf(D2), EPSF);
      const float w2raw = sqrtf(W22);
      const float w2n = fmaxf(w2raw, EPSF);
      const float nu = (w2raw <= EPSF) ? 0.f : (tanhf(w2n/dn*artanh_c(dn))/w2n);
      const float Y2f = nu*nu*W22, XYf = nu*HW;
      const float cAf = 1.f + 2.f*XYf + Y2f, cBf = 1.f - H2;
      const float denf = fmaxf(1.f + 2.f*XYf + H2*Y2f, EPSF), idf = 1.f/denf;
      const float hnew = (cAf*hj + cBf*(nu*w2el))*idf;
      outbuf[(size_t)(t*B_ + b)*H_ + tid] = hnew;
      h[tid] = hnew;
    } else {
      __syncthreads(); // bar5
      __syncthreads(); // bar6
    }
    __syncthreads();   // bar7: h visible for next step
  }
  if (isz) hlast[b*H_ + tid] = h[tid];
}

extern "C" void kernel_launch(void* const* d_in, const int* in_sizes, int n_in,
                              void* d_out, int out_size, void* d_ws, size_t ws_size,
                              hipStream_t stream){
  (void)in_sizes; (void)n_in; (void)out_size; (void)ws_size;
  const float* input = (const float*)d_in[0];
  const float* h0    = (const float*)d_in[1];
  const float* wih1  = (const float*)d_in[2];
  const float* wih2  = (const float*)d_in[3];
  const float* whh1  = (const float*)d_in[4];
  const float* whh2  = (const float*)d_in[5];
  const float* bias1 = (const float*)d_in[6];
  const float* bias2 = (const float*)d_in[7];
  float* out = (float*)d_out;

  // ws: WihT 786432 f | Dbuf 25165824 f | Wzr4 131072 h2x2 | Whc4 65536 h2x2 (~105 MB)
  float* A_   = (float*)d_ws;
  float* Dbuf = A_ + 786432;
  h2x2* Wzr4 = (h2x2*)(Dbuf + 25165824);
  h2x2* Whc4 = Wzr4 + 131072;

  float* out1 = out;                           // staged; consumed before scan-2 overwrites
  float* ht   = out + (size_t)T_ * B_ * H_;

  // layer 1
  k_prep_ih<<<3072, 256, 0, stream>>>(wih1, A_);
  k_gemm<<<dim3(256, 24), 256, 0, stream>>>(input, A_, Dbuf);
  k_nonlin<<<T_*B_, 64, 0, stream>>>(input, Dbuf);
  k_prep_hh4<<<768, 256, 0, stream>>>(whh1, Wzr4, Whc4);
  k_scan<<<B_, 1024, 0, stream>>>(Dbuf, Wzr4, Whc4, bias1, h0, out1, ht);

  // layer 2
  k_prep_ih<<<3072, 256, 0, stream>>>(wih2, A_);
  k_gemm<<<dim3(256, 24), 256, 0, stream>>>(out1, A_, Dbuf);
  k_nonlin<<<T_*B_, 64, 0, stream>>>(out1, Dbuf);
  k_prep_hh4<<<768, 256, 0, stream>>>(whh2, Wzr4, Whc4);
  k_scan<<<B_, 1024, 0, stream>>>(Dbuf, Wzr4, Whc4, bias2, h0 + B_*H_, out, ht + B_*H_);
}

// Round 4
// 15072.131 us; speedup vs baseline: 1.2834x; 1.0948x over previous
//
#include <hip/hip_runtime.h>
#include <hip/hip_fp16.h>
#include <math.h>
#include <stdint.h>

// MobiusGRU T=256 B=64 D=H=512, 2 layers.
// R4 vs R3: drive k_scan to its per-CU L2-stream floor (~11us/step):
//  - v_dot2_f32_f16 matvecs (h, rhs in LDS as f16)
//  - mu pulled out of phase-B (linearity) -> one barrier merged (6/step)
//  - [slot][wave] reduce layout, combines via broadcast ds_read_b128

#define T_  256
#define B_  64
#define H_  512
#define G3_ 1536
#define EPSF 1e-15f
#define CLIPF (1.0f - 1e-5f)

struct __align__(8) h2x2 { __half2 a, b; };

typedef _Float16 v2h __attribute__((ext_vector_type(2)));

__device__ __forceinline__ float fdot2_(unsigned int w, unsigned int h, float c){
#if __has_builtin(__builtin_amdgcn_fdot2)
  return __builtin_amdgcn_fdot2(__builtin_bit_cast(v2h, w), __builtin_bit_cast(v2h, h), c, false);
#else
  const __half2 wh = __builtin_bit_cast(__half2, w);
  const __half2 hh = __builtin_bit_cast(__half2, h);
  return c + __low2float(wh)*__low2float(hh) + __high2float(wh)*__high2float(hh);
#endif
}

__device__ __forceinline__ float artanh_c(float x){
  x = fminf(fmaxf(x, -CLIPF), CLIPF);
  return 0.5f * logf((1.0f + x) / (1.0f - x));
}
__device__ __forceinline__ float sigmoidf_(float x){ return 1.0f/(1.0f+expf(-x)); }
__device__ __forceinline__ float hsum4(float4 v){ return (v.x+v.y)+(v.z+v.w); }

// shuffle-reduce NS values across the wave; lane0 stores red[s*STRIDE + wave]
template<int NS, int STRIDE>
__device__ __forceinline__ void wave_reduce_store(float (&v)[NS], float* red, int tid){
  #pragma unroll
  for (int off = 32; off > 0; off >>= 1)
    #pragma unroll
    for (int s = 0; s < NS; s++) v[s] += __shfl_xor(v[s], off);
  if ((tid & 63) == 0)
    #pragma unroll
    for (int s = 0; s < NS; s++) red[s*STRIDE + (tid >> 6)] = v[s];
}

// ---- transpose weight_ih [1536][512] -> WihT [512][1536]
__global__ void k_prep_ih(const float* __restrict__ Wih, float* __restrict__ WihT){
  int i = blockIdx.x * blockDim.x + threadIdx.x;
  if (i >= H_ * G3_) return;
  int k = i / G3_, n = i % G3_;
  WihT[i] = Wih[n * H_ + k];
}

// ---- weight_hh -> packed f16, 4-k-wide: Wzr4[k4][1024 cols z|r], Whc4[k4][512]
// weight_hh row split: [0:512)=W_hr, [512:1024)=W_hh(cand), [1024:1536)=W_hz
__global__ void k_prep_hh4(const float* __restrict__ Whh, h2x2* __restrict__ Wzr4,
                           h2x2* __restrict__ Whc4){
  int i = blockIdx.x * blockDim.x + threadIdx.x;   // 196608 total
  if (i < 128*1024){
    int k4 = i >> 10, col = i & 1023;
    int row = (col < 512) ? (1024 + col) : (col - 512);   // z | r
    const float* s = Whh + row*H_ + 4*k4;
    h2x2 w;
    w.a = __halves2half2(__float2half_rn(s[0]), __float2half_rn(s[1]));
    w.b = __halves2half2(__float2half_rn(s[2]), __float2half_rn(s[3]));
    Wzr4[i] = w;
  } else {
    int i2 = i - 128*1024;
    if (i2 < 128*512){
      int k4 = i2 >> 9, col = i2 & 511;
      const float* s = Whh + (H_ + col)*H_ + 4*k4;
      h2x2 w;
      w.a = __halves2half2(__float2half_rn(s[0]), __float2half_rn(s[1]));
      w.b = __halves2half2(__float2half_rn(s[2]), __float2half_rn(s[3]));
      Whc4[i2] = w;
    }
  }
}

// ---- tiled f32 GEMM: C[16384][1536] = A[16384][512] * Bt[512][1536]
__global__ __launch_bounds__(256) void k_gemm(const float* __restrict__ A,
                                              const float* __restrict__ Bt,
                                              float* __restrict__ C){
  const int N = G3_, K = H_;
  const int mbase = blockIdx.x * 64, nbase = blockIdx.y * 64;
  __shared__ float As[32][65];
  __shared__ float Bs[32][65];
  const int tid = threadIdx.x;
  const int tm = tid >> 4, tn = tid & 15;
  float acc[4][4] = {};
  for (int k0 = 0; k0 < K; k0 += 32){
    #pragma unroll
    for (int i = 0; i < 8; i++){
      int e = tid + 256*i;
      int m = e >> 5, k = e & 31;
      As[k][m] = A[(size_t)(mbase + m) * K + k0 + k];
      int kk = e >> 6, n = e & 63;
      Bs[kk][n] = Bt[(size_t)(k0 + kk) * N + nbase + n];
    }
    __syncthreads();
    #pragma unroll
    for (int kk = 0; kk < 32; kk++){
      float av[4], bv[4];
      #pragma unroll
      for (int i = 0; i < 4; i++) av[i] = As[kk][tm*4+i];
      #pragma unroll
      for (int j = 0; j < 4; j++) bv[j] = Bs[kk][tn*4+j];
      #pragma unroll
      for (int i = 0; i < 4; i++)
        #pragma unroll
        for (int j = 0; j < 4; j++)
          acc[i][j] = fmaf(av[i], bv[j], acc[i][j]);
    }
    __syncthreads();
  }
  #pragma unroll
  for (int i = 0; i < 4; i++)
    #pragma unroll
    for (int j = 0; j < 4; j++)
      C[(size_t)(mbase + tm*4 + i) * N + nbase + tn*4 + j] = acc[i][j];
}

// ---- mobius_matvec tail on Ux rows
__global__ void k_nonlin(const float* __restrict__ X, float* __restrict__ D){
  const int row = blockIdx.x;
  const int lane = threadIdx.x;
  const float* x = X + (size_t)row * H_;
  float s = 0.0f;
  for (int k = lane; k < H_; k += 64){ float v = x[k]; s = fmaf(v, v, s); }
  #pragma unroll
  for (int off = 32; off > 0; off >>= 1) s += __shfl_xor(s, off);
  const float xn = fmaxf(sqrtf(s), EPSF);
  const float art = artanh_c(xn);
  float* drow = D + (size_t)row * G3_;
  for (int g = 0; g < 3; g++){
    float* mx = drow + g * H_;
    float s2 = 0.0f;
    for (int k = lane; k < H_; k += 64){ float v = mx[k]; s2 = fmaf(v, v, s2); }
    #pragma unroll
    for (int off = 32; off > 0; off >>= 1) s2 += __shfl_xor(s2, off);
    const float raw = sqrtf(s2);
    const float mn = fmaxf(raw, EPSF);
    const float scale = (raw <= EPSF) ? 0.0f : (tanhf(mn / xn * art) / mn);
    for (int k = lane; k < H_; k += 64) mx[k] *= scale;
  }
}

// ---- sequential scan: 1 WG (1024 thr) per batch row
// red regions (floats): R1 [0,96) 6 slots x16; R2 [96,112) 1x16; R3 [112,176) 8x8; R4 [176,200) 3x8
__global__ __launch_bounds__(1024, 1) void k_scan(
    const float* __restrict__ D,        // Ux' [T*B][1536]: r|c|z col blocks
    const h2x2* __restrict__ Wzr4,      // [128 k4][1024 cols] z|r, f16
    const h2x2* __restrict__ Whc4,      // [128 k4][512 cols] candidate, f16
    const float* __restrict__ bias,     // [3][512] = b_r, b_c, b_z
    const float* __restrict__ h0,
    float* __restrict__ outbuf,         // [T][64][512]
    float* __restrict__ hlast)
{
  const int b = blockIdx.x, tid = threadIdx.x;
  __shared__ __align__(16) float h[H_];
  __shared__ __align__(16) __half hh[H_];     // h as f16 (for dot2)
  __shared__ __align__(16) __half rhs_h[H_];  // raw r.*h as f16 (mu pulled out)
  __shared__ float zbuf[H_];
  __shared__ __align__(16) float ph[1024];
  __shared__ __align__(16) float red[200];
  const int wave = tid >> 6;
  const bool isz = tid < 512;          // lo half: z gate + all phase-B tail work
  const int j = isz ? tid : tid - 512;
  if (isz){
    const float hv0 = h0[b*H_ + tid];
    h[tid] = hv0;
    hh[tid] = __float2half_rn(hv0);
  }
  const float bval = bias[isz ? (2*H_ + j) : j];     // own gate bias elem (z|r)
  const float bcj  = isz ? bias[H_ + tid] : 0.f;     // candidate bias elem
  // loop-invariant bias norms
  float B2, BC2;
  {
    float vb[2] = { bval*bval, bcj*bcj };
    wave_reduce_store<2,16>(vb, red, tid);
    __syncthreads();
    const float4* p0 = (const float4*)red;        // slot0 [16]
    const float4* p1 = (const float4*)(red + 16); // slot1 [16]
    B2  = isz ? (hsum4(p0[0]) + hsum4(p0[1])) : (hsum4(p0[2]) + hsum4(p0[3]));
    BC2 = hsum4(p1[0]) + hsum4(p1[1]);
    __syncthreads();
  }

  const int colB = tid & 511, halfk = tid >> 9;
  const uint2* wpA = (const uint2*)Wzr4 + tid;
  const uint2* wpB = (const uint2*)Whc4 + (size_t)(halfk*64)*512 + colB;
  const uint2* h4  = (const uint2*)hh;       // 128 entries of 4 halves
  const uint2* r4  = (const uint2*)rhs_h + halfk*64;
  const float* Urow0 = D + (size_t)b * G3_;

  for (int t = 0; t < T_; t++){
    const float* U = Urow0 + (size_t)t * (B_ * G3_);
    const float y = U[isz ? (2*H_ + j) : j];

    // ---- phase A: a = sum_k W[k][tid] h[k]  (col tid of z|r), f16 dot2
    float a0 = 0.f, a1 = 0.f;
    #pragma unroll 8
    for (int k4 = 0; k4 < 128; k4++){
      const uint2 w = wpA[k4*1024];
      const uint2 hv2 = h4[k4];
      a0 = fdot2_(w.x, hv2.x, a0);
      a1 = fdot2_(w.y, hv2.y, a1);
    }
    const float a = a0 + a1;
    const float hv = isz ? h[tid] : 0.f;
    // R1: slots {h2, a2, ay, y2, ab, yb} — gate dots per half (z waves 0-7, r waves 8-15)
    float v6[6] = { hv*hv, a*a, a*y, y*y, a*bval, y*bval };
    wave_reduce_store<6,16>(v6, red, tid);
    __syncthreads();   // bar1
    float H2, A2, AY, Yy2, AB, YB;
    {
      const float4* p = (const float4*)red;
      H2 = hsum4(p[0]) + hsum4(p[1]) + hsum4(p[2]) + hsum4(p[3]);
      const int o = isz ? 0 : 2;   // float4 index offset within each slot
      const float4* p1 = (const float4*)(red + 16);
      const float4* p2 = (const float4*)(red + 32);
      const float4* p3 = (const float4*)(red + 48);
      const float4* p4 = (const float4*)(red + 64);
      const float4* p5 = (const float4*)(red + 80);
      A2  = hsum4(p1[o]) + hsum4(p1[o+1]);
      AY  = hsum4(p2[o]) + hsum4(p2[o+1]);
      Yy2 = hsum4(p3[o]) + hsum4(p3[o+1]);
      AB  = hsum4(p4[o]) + hsum4(p4[o+1]);
      YB  = hsum4(p5[o]) + hsum4(p5[o+1]);
    }
    const float xn = fmaxf(sqrtf(H2), EPSF);
    const float art_h = artanh_c(xn);
    const float mraw = sqrtf(A2);
    const float mnc = fmaxf(mraw, EPSF);
    const float alpha = (mraw <= EPSF) ? 0.f : (tanhf(mnc/xn*art_h)/mnc);
    // t1 = (alpha*a) (+) y ; t2 = t1 (+) b ; gate = sigmoid(artanh(|t2|)/|t2| * t2el)
    const float X2 = alpha*alpha*A2, XY = alpha*AY, XB = alpha*AB;
    const float cA1 = 1.f + 2.f*XY + Yy2, cB1 = 1.f - X2;
    const float den1 = fmaxf(1.f + 2.f*XY + X2*Yy2, EPSF), id1 = 1.f/den1;
    const float T2 = fmaxf((cA1*cA1*X2 + 2.f*cA1*cB1*XY + cB1*cB1*Yy2)*id1*id1, 0.f);
    const float TB = (cA1*XB + cB1*YB)*id1;
    const float cA2 = 1.f + 2.f*TB + B2, cB2 = 1.f - T2;
    const float den2 = fmaxf(1.f + 2.f*TB + T2*B2, EPSF), id2 = 1.f/den2;
    const float U2 = fmaxf((cA2*cA2*T2 + 2.f*cA2*cB2*TB + cB2*cB2*B2)*id2*id2, 0.f);
    const float un = fmaxf(sqrtf(U2), EPSF);
    const float lsc = artanh_c(un)/un;
    const float t1el = (cA1*(alpha*a) + cB1*y)*id1;
    const float uel  = (cA2*t1el + cB2*bval)*id2;
    const float g = sigmoidf_(lsc*uel);
    float wv = 0.f;
    if (isz) zbuf[j] = g;
    else { wv = g*h[j]; rhs_h[j] = __float2half_rn(wv); }  // raw wv; mu applied later
    // R2: ||r.*h||^2
    float v1[1] = { wv*wv };
    wave_reduce_store<1,16>(v1, red + 96, tid);
    __syncthreads();   // bar2 (rhs_h, zbuf, R2 partials all visible)
    float W2;
    {
      const float4* p = (const float4*)(red + 96);
      W2 = hsum4(p[2]) + hsum4(p[3]);   // waves 8-15 carry data
    }
    const float wraw = sqrtf(W2);
    const float wn = fmaxf(wraw, EPSF);
    const float mu = (wraw <= EPSF) ? 0.f : (tanhf(wn/xn*art_h)/wn);
    const float rhn = fmaxf(mu*wraw, EPSF);

    // ---- phase B: cpart = sum_k Whc[k][colB] rhs[k] (split-k x2), scaled by mu
    float c0 = 0.f, c1 = 0.f;
    #pragma unroll 8
    for (int k4i = 0; k4i < 64; k4i++){
      const uint2 w = wpB[k4i*512];
      const uint2 rr = r4[k4i];
      c0 = fdot2_(w.x, rr.x, c0);
      c1 = fdot2_(w.y, rr.y, c1);
    }
    ph[tid] = mu * (c0 + c1);
    __syncthreads();   // bar3
    if (wave < 8){
      const float cel  = ph[tid] + ph[tid + 512];
      const float ycel = U[H_ + tid];
      const float hj   = h[tid];
      // R3: {c2, cy, y2, cb, yb, hc, hy, hb}
      float v8[8];
      v8[0]=cel*cel; v8[1]=cel*ycel; v8[2]=ycel*ycel; v8[3]=cel*bcj;
      v8[4]=ycel*bcj; v8[5]=hj*cel; v8[6]=hj*ycel; v8[7]=hj*bcj;
      wave_reduce_store<8,8>(v8, red + 112, tid);
      __syncthreads(); // bar4
      float C2,CY,Y2c,CB,YBc,HC,HYd,HBd;
      {
        const float4* p = (const float4*)(red + 112);
        C2 =hsum4(p[0]) +hsum4(p[1]);  CY =hsum4(p[2]) +hsum4(p[3]);
        Y2c=hsum4(p[4]) +hsum4(p[5]);  CB =hsum4(p[6]) +hsum4(p[7]);
        YBc=hsum4(p[8]) +hsum4(p[9]);  HC =hsum4(p[10])+hsum4(p[11]);
        HYd=hsum4(p[12])+hsum4(p[13]); HBd=hsum4(p[14])+hsum4(p[15]);
      }
      const float craw = sqrtf(C2);
      const float cmn2 = fmaxf(craw, EPSF);
      const float alc = (craw <= EPSF) ? 0.f : (tanhf(cmn2/rhn*artanh_c(rhn))/cmn2);
      const float X2c = alc*alc*C2, XYc = alc*CY, XBc = alc*CB, HXc = alc*HC;
      const float cA1c = 1.f + 2.f*XYc + Y2c, cB1c = 1.f - X2c;
      const float den1c = fmaxf(1.f + 2.f*XYc + X2c*Y2c, EPSF), id1c = 1.f/den1c;
      const float T2c = fmaxf((cA1c*cA1c*X2c + 2.f*cA1c*cB1c*XYc + cB1c*cB1c*Y2c)*id1c*id1c, 0.f);
      const float TBc = (cA1c*XBc + cB1c*YBc)*id1c;
      const float HT1 = (cA1c*HXc + cB1c*HYd)*id1c;
      const float cA2c = 1.f + 2.f*TBc + BC2, cB2c = 1.f - T2c;
      const float den2c = fmaxf(1.f + 2.f*TBc + T2c*BC2, EPSF), id2c = 1.f/den2c;
      const float HTL2 = fmaxf((cA2c*cA2c*T2c + 2.f*cA2c*cB2c*TBc + cB2c*cB2c*BC2)*id2c*id2c, 0.f);
      const float HHTL = (cA2c*HT1 + cB2c*HBd)*id2c;
      const float cAd = 1.f - 2.f*HHTL + HTL2, cBd = 1.f - H2;
      const float dend = fmaxf(1.f - 2.f*HHTL + H2*HTL2, EPSF), idd = 1.f/dend;
      const float t1cel = (cA1c*(alc*cel) + cB1c*ycel)*id1c;
      const float htlel = (cA2c*t1cel + cB2c*bcj)*id2c;
      const float del = (cAd*(-hj) + cBd*htlel)*idd;
      const float zv = zbuf[tid];
      const float w2el = zv*del;
      // R4: {|delta|^2, |z.*delta|^2, h.(z.*delta)}
      float v3[3] = { del*del, w2el*w2el, hj*w2el };
      wave_reduce_store<3,8>(v3, red + 176, tid);
      __syncthreads(); // bar5
      float D2, W22, HW;
      {
        const float4* p = (const float4*)(red + 176);
        D2 = hsum4(p[0]) + hsum4(p[1]);
        W22= hsum4(p[2]) + hsum4(p[3]);
        HW = hsum4(p[4]) + hsum4(p[5]);
      }
      const float dn = fmaxf(sqrtf(D2), EPSF);
      const float w2raw = sqrtf(W22);
      const float w2n = fmaxf(w2raw, EPSF);
      const float nu = (w2raw <= EPSF) ? 0.f : (tanhf(w2n/dn*artanh_c(dn))/w2n);
      const float Y2f = nu*nu*W22, XYf = nu*HW;
      const float cAf = 1.f + 2.f*XYf + Y2f, cBf = 1.f - H2;
      const float denf = fmaxf(1.f + 2.f*XYf + H2*Y2f, EPSF), idf = 1.f/denf;
      const float hnew = (cAf*hj + cBf*(nu*w2el))*idf;
      outbuf[(size_t)(t*B_ + b)*H_ + tid] = hnew;
      h[tid] = hnew;
      hh[tid] = __float2half_rn(hnew);
    } else {
      __syncthreads(); // bar4
      __syncthreads(); // bar5
    }
    __syncthreads();   // bar6: h/hh visible for next step
  }
  if (isz) hlast[b*H_ + tid] = h[tid];
}

extern "C" void kernel_launch(void* const* d_in, const int* in_sizes, int n_in,
                              void* d_out, int out_size, void* d_ws, size_t ws_size,
                              hipStream_t stream){
  (void)in_sizes; (void)n_in; (void)out_size; (void)ws_size;
  const float* input = (const float*)d_in[0];
  const float* h0    = (const float*)d_in[1];
  const float* wih1  = (const float*)d_in[2];
  const float* wih2  = (const float*)d_in[3];
  const float* whh1  = (const float*)d_in[4];
  const float* whh2  = (const float*)d_in[5];
  const float* bias1 = (const float*)d_in[6];
  const float* bias2 = (const float*)d_in[7];
  float* out = (float*)d_out;

  // ws: WihT 786432 f | Dbuf 25165824 f | Wzr4 131072 h2x2 | Whc4 65536 h2x2 (~105 MB)
  float* A_   = (float*)d_ws;
  float* Dbuf = A_ + 786432;
  h2x2* Wzr4 = (h2x2*)(Dbuf + 25165824);
  h2x2* Whc4 = Wzr4 + 131072;

  float* out1 = out;                           // staged; consumed before scan-2 overwrites
  float* ht   = out + (size_t)T_ * B_ * H_;

  // layer 1
  k_prep_ih<<<3072, 256, 0, stream>>>(wih1, A_);
  k_gemm<<<dim3(256, 24), 256, 0, stream>>>(input, A_, Dbuf);
  k_nonlin<<<T_*B_, 64, 0, stream>>>(input, Dbuf);
  k_prep_hh4<<<768, 256, 0, stream>>>(whh1, Wzr4, Whc4);
  k_scan<<<B_, 1024, 0, stream>>>(Dbuf, Wzr4, Whc4, bias1, h0, out1, ht);

  // layer 2
  k_prep_ih<<<3072, 256, 0, stream>>>(wih2, A_);
  k_gemm<<<dim3(256, 24), 256, 0, stream>>>(out1, A_, Dbuf);
  k_nonlin<<<T_*B_, 64, 0, stream>>>(out1, Dbuf);
  k_prep_hh4<<<768, 256, 0, stream>>>(whh2, Wzr4, Whc4);
  k_scan<<<B_, 1024, 0, stream>>>(Dbuf, Wzr4, Whc4, bias2, h0 + B_*H_, out, ht + B_*H_);
}